// Round 5
// baseline (159.831 us; speedup 1.0000x reference)
//
#include <hip/hip_runtime.h>
#include <math.h>
#include <stdint.h>

#define ALPHA 0.2f

typedef __attribute__((ext_vector_type(8))) short bf16x8;
typedef __attribute__((ext_vector_type(4))) float f32x4;

__device__ __forceinline__ uint32_t pack_bf16(float a, float b) {
    return ((__float_as_uint(a) + 0x8000u) >> 16) |
           ((__float_as_uint(b) + 0x8000u) & 0xFFFF0000u);
}

// ---------------------------------------------------------------------------
// Kernel 1: k_wh — Wh = (x^T)W fused transpose-GEMM, emitting Wh directly in
// MFMA B-fragment layout (bf16), plus fp32 Wh1/Wh2 score vectors.
//
// Grid 512 = (8 b x 64 j-tiles of 16 rows). Block 512 = 8 waves, wave = t.
// Lane (q = l>>4, om = l&15): acc[jj][nt] for j = jt*16 + q*4 + jj,
// o = nt*16 + om. Each block fills HALF of the k=32 B-frags (jt32 = jt>>1):
// lane writes one uint2 (frag regs 2(q&1), 2(q&1)+1) at frag-lane
// q8 = (jt&1)*2 + (q>>1), om — coalesced 8B stores, disjoint halves.
//
// LDS: xs 32 KB ([jl][t][k ^ (jl>>2)<<2], staging & reads both <=2-way),
//      Wv 34.8 KB ([o][k] pad 68, group-swizzled by (o>>3)&7 so the
//      transpose STAGING is 2-way instead of 32-way — the r4 bug).
// 67 KB total -> 2 blocks/CU, 16 waves/CU.
// ---------------------------------------------------------------------------
__global__ __launch_bounds__(512, 4) void k_wh(const float* __restrict__ x,
                                               const float* __restrict__ W,
                                               const float* __restrict__ a,
                                               uint4* __restrict__ Whf,
                                               float* __restrict__ Wh1,
                                               float* __restrict__ Wh2) {
    __shared__ float xs[16 * 512];        // 32 KB
    __shared__ float Wv[128 * 68];        // 34.8 KB

    const int tid = threadIdx.x;
    const int b   = blockIdx.x & 7;
    const int jt  = blockIdx.x >> 3;      // 0..63 (16-row tiles)

    // stage x: 16 rows x 512 floats = 2048 float4
    const float4* xg4 = (const float4*)(x + (size_t)(b * 1024 + jt * 16) * 512);
    #pragma unroll
    for (int i = 0; i < 4; ++i) {
        int    idx = tid + i * 512;       // 0..2047
        float4 v   = xg4[idx];
        int jl  = idx >> 7;               // 0..15
        int rem = idx & 127;
        int f   = rem >> 1;               // 0..63
        int tq  = rem & 1;                // t = tq*4 + c
        int kk  = f ^ ((jl >> 2) << 2);   // swizzle by consumer k-quad
        float* dst = &xs[jl * 512 + (tq * 4) * 64 + kk];
        dst[0]   = v.x;
        dst[64]  = v.y;
        dst[128] = v.z;
        dst[192] = v.w;
    }
    // stage Wv[o][k] = W[k][o], k-group swizzled by (o>>3)&7 (2-way staging)
    const float4* Wg4 = (const float4*)W;
    #pragma unroll
    for (int i = 0; i < 4; ++i) {
        int    idx = tid + i * 512;       // 0..2047
        float4 v   = Wg4[idx];
        int k  = idx >> 5;                // 0..63
        int o0 = (idx & 31) * 4;
        #pragma unroll
        for (int c = 0; c < 4; ++c) {
            int o   = o0 + c;
            int adr = o * 68 + ((((k >> 2) ^ ((o >> 3) & 7)) << 2) | (k & 3));
            Wv[adr] = (&v.x)[c];
        }
    }
    __syncthreads();

    const int w  = tid >> 6;              // wave = t (0..7)
    const int l  = tid & 63;
    const int q  = l >> 4;
    const int om = l & 15;
    const int t  = w;

    float acc[4][8];                      // [jj][nt]
    #pragma unroll
    for (int jj = 0; jj < 4; ++jj)
        #pragma unroll
        for (int nt = 0; nt < 8; ++nt) acc[jj][nt] = 0.f;

    for (int kc = 0; kc < 64; kc += 4) {
        float4 xv[4], wv[8];
        const int kx = kc ^ (q << 2);
        #pragma unroll
        for (int jj = 0; jj < 4; ++jj)
            xv[jj] = *(const float4*)&xs[(q * 4 + jj) * 512 + t * 64 + kx];
        #pragma unroll
        for (int nt = 0; nt < 8; ++nt) {
            int og  = nt * 16 + om;
            int grp = (kc >> 2) ^ ((nt * 2 + (om >> 3)) & 7);
            wv[nt]  = *(const float4*)&Wv[og * 68 + grp * 4];
        }
        #pragma unroll
        for (int jj = 0; jj < 4; ++jj) {
            #pragma unroll
            for (int nt = 0; nt < 8; ++nt) {
                float s = acc[jj][nt];
                s = fmaf(xv[jj].x, wv[nt].x, s);
                s = fmaf(xv[jj].y, wv[nt].y, s);
                s = fmaf(xv[jj].z, wv[nt].z, s);
                s = fmaf(xv[jj].w, wv[nt].w, s);
                acc[jj][nt] = s;
            }
        }
    }

    const int bt = b * 8 + t;

    // Wh1/Wh2: dot with a1/a2 over o, reduce across the 16 om-lanes
    float a1v[8], a2v[8];
    #pragma unroll
    for (int nt = 0; nt < 8; ++nt) {
        a1v[nt] = a[nt * 16 + om];
        a2v[nt] = a[128 + nt * 16 + om];
    }
    #pragma unroll
    for (int jj = 0; jj < 4; ++jj) {
        float s1 = 0.f, s2 = 0.f;
        #pragma unroll
        for (int nt = 0; nt < 8; ++nt) {
            s1 = fmaf(acc[jj][nt], a1v[nt], s1);
            s2 = fmaf(acc[jj][nt], a2v[nt], s2);
        }
        #pragma unroll
        for (int off = 1; off < 16; off <<= 1) {
            s1 += __shfl_xor(s1, off);
            s2 += __shfl_xor(s2, off);
        }
        if (om == 0) {
            int j = jt * 16 + q * 4 + jj;
            Wh1[bt * 1024 + j] = s1;
            Wh2[bt * 1024 + j] = s2;
        }
    }

    // frag half-store: uint2 per nt (regs 2(q&1), 2(q&1)+1 of frag-lane q8,om)
    const int    q8l   = ((jt & 1) << 1) | (q >> 1);
    const int    l8    = (q8l << 4) | om;
    const size_t fbase = (size_t)(bt * 32 + (jt >> 1)) * 8;
    #pragma unroll
    for (int nt = 0; nt < 8; ++nt) {
        uint2 st;
        st.x = pack_bf16(acc[0][nt], acc[1][nt]);
        st.y = pack_bf16(acc[2][nt], acc[3][nt]);
        char* p = (char*)(Whf + (fbase + nt) * 64 + l8) + ((q & 1) << 3);
        *(uint2*)p = st;
    }
}

// ---------------------------------------------------------------------------
// Kernel 2: adj -> byte bitmask adjb[i][j/8] (128 KB)
// ---------------------------------------------------------------------------
__global__ __launch_bounds__(256) void k_adjb(const float* __restrict__ adj,
                                              unsigned char* __restrict__ adjb) {
    int idx = blockIdx.x * 256 + threadIdx.x;       // 0..131071
    const float4* a4 = (const float4*)adj + idx * 2;
    float4 v0 = a4[0], v1 = a4[1];
    unsigned int by = 0;
    by |= (v0.x > 0.f) ? 1u : 0u;
    by |= (v0.y > 0.f) ? 2u : 0u;
    by |= (v0.z > 0.f) ? 4u : 0u;
    by |= (v0.w > 0.f) ? 8u : 0u;
    by |= (v1.x > 0.f) ? 16u : 0u;
    by |= (v1.y > 0.f) ? 32u : 0u;
    by |= (v1.z > 0.f) ? 64u : 0u;
    by |= (v1.w > 0.f) ? 128u : 0u;
    adjb[idx] = (unsigned char)by;
}

// ---------------------------------------------------------------------------
// Kernel 3: k_agg — dense flash aggregation, FACTORED scores (no exp in the
// inner loop) + MFMA PV + ones-column MFMA for the softmax denominator.
//
//   p_ij = exp(lrelu(h1_i+h2_j) - mp_i)
//        = (h1+h2>0) ? A_i*E_j : B_i*F_j,   branch test E_j > G_i
//   A=exp(h1-mp), B=exp(.2h1-mp), G=exp(-h1); E=exp(h2), F=exp(.2h2) staged.
//   mp_i = lrelu(h1_i + max_j h2_j)  =>  p <= 1 for ALL (i,j): no overflow.
//   l_i = sum_j p via mfma(P, ones) — lands in D-layout rows = epilogue rows.
//
// Grid 512: blockIdx = ((itile*8 + t)*8 + b) -> XCD = b (Whf plane pinned).
// Block 512 = 8 waves; wave w owns rows [i0+w*16, +16). 16 waves/CU.
// ---------------------------------------------------------------------------
__global__ __launch_bounds__(512, 4) void k_agg(const uint4* __restrict__ Whf,
                                                const float* __restrict__ Wh1,
                                                const float* __restrict__ Wh2,
                                                const unsigned char* __restrict__ adjb,
                                                float* __restrict__ out) {
    __shared__ __attribute__((aligned(16))) float2 efs[1024];   // 8 KB  [E,F]
    __shared__ unsigned int adjs_u[128 * 33];                   // 16.5 KB
    __shared__ float wh1s[128];
    __shared__ float m2s[8];

    const int tid   = threadIdx.x;
    const int b     = blockIdx.x & 7;
    const int t     = (blockIdx.x >> 3) & 7;
    const int itile = blockIdx.x >> 6;            // 0..7
    const int bt    = b * 8 + t;
    const int i0    = itile * 128;

    const int w = tid >> 6;                       // wave 0..7
    const int l = tid & 63;
    const int q = l >> 4;                         // k-quad
    const int m = l & 15;

    // stage E/F (+ running max of h2), Wh1 slice, adj bitmask slice
    const float* wh2g = Wh2 + bt * 1024;
    float mx = -1e30f;
    for (int j = tid; j < 1024; j += 512) {
        float h2 = wh2g[j];
        float2 ef;
        ef.x = __expf(h2);
        ef.y = __expf(ALPHA * h2);
        efs[j] = ef;
        mx = fmaxf(mx, h2);
    }
    #pragma unroll
    for (int off = 1; off < 64; off <<= 1) mx = fmaxf(mx, __shfl_xor(mx, off));
    if (l == 0) m2s[w] = mx;
    if (tid < 128) wh1s[tid] = Wh1[bt * 1024 + i0 + tid];
    const unsigned int* adjg = (const unsigned int*)(adjb + i0 * 128);
    for (int idx = tid; idx < 4096; idx += 512)
        adjs_u[(idx >> 5) * 33 + (idx & 31)] = adjg[idx];
    __syncthreads();

    float M2 = m2s[0];
    #pragma unroll
    for (int i = 1; i < 8; ++i) M2 = fmaxf(M2, m2s[i]);

    const int   row = w * 16 + m;                 // A-side row of this lane
    const float h1  = wh1s[row];
    const float e0  = h1 + M2;
    const float mp  = fmaxf(e0, ALPHA * e0);
    const float Af  = __expf(h1 - mp);
    const float Bf  = __expf(ALPHA * h1 - mp);
    const float G   = __expf(-h1);

    f32x4 acc[8];
    #pragma unroll
    for (int nt = 0; nt < 8; ++nt) acc[nt] = (f32x4){0.f, 0.f, 0.f, 0.f};
    f32x4 accl = (f32x4){0.f, 0.f, 0.f, 0.f};

    bf16x8 ones;
    #pragma unroll
    for (int i = 0; i < 8; ++i) ones[i] = (short)0x3F80;

    const uint4* bfg = Whf + (size_t)bt * 32 * 8 * 64 + l;

    for (int s = 0; s < 32; ++s) {
        // 8 (E,F) pairs for j = s*32 + q*8 + jj  (16-lane broadcast, 2-way bank)
        const float* eb = (const float*)&efs[s * 32 + q * 8];
        float4 ef01 = *(const float4*)(eb + 0);
        float4 ef23 = *(const float4*)(eb + 4);
        float4 ef45 = *(const float4*)(eb + 8);
        float4 ef67 = *(const float4*)(eb + 12);
        const unsigned int dw = adjs_u[row * 33 + s];  // bit q*8+jj = adj(row, j)

        float E[8], F[8];
        E[0] = ef01.x; F[0] = ef01.y; E[1] = ef01.z; F[1] = ef01.w;
        E[2] = ef23.x; F[2] = ef23.y; E[3] = ef23.z; F[3] = ef23.w;
        E[4] = ef45.x; F[4] = ef45.y; E[5] = ef45.z; F[5] = ef45.w;
        E[6] = ef67.x; F[6] = ef67.y; E[7] = ef67.z; F[7] = ef67.w;

        float p[8];
        #pragma unroll
        for (int jj = 0; jj < 8; ++jj) {
            bool  cond = E[jj] > G;                       // e = h1+h2 > 0
            float pr   = (cond ? Af : Bf) * (cond ? E[jj] : F[jj]);
            p[jj] = ((dw >> (q * 8 + jj)) & 1u) ? pr : 0.0f;
        }

        union { uint32_t u[4]; bf16x8 v; } pk;
        #pragma unroll
        for (int pr2 = 0; pr2 < 4; ++pr2)
            pk.u[pr2] = pack_bf16(p[2 * pr2], p[2 * pr2 + 1]);

        const uint4* bp = bfg + (size_t)s * 8 * 64;
        #pragma unroll
        for (int nt = 0; nt < 8; ++nt) {
            union { uint4 u; bf16x8 v; } br;
            br.u = bp[nt * 64];
            acc[nt] = __builtin_amdgcn_mfma_f32_16x16x32_bf16(pk.v, br.v, acc[nt], 0, 0, 0);
        }
        accl = __builtin_amdgcn_mfma_f32_16x16x32_bf16(pk.v, ones, accl, 0, 0, 0);
    }

    // epilogue: D-layout rows r = q*4+reg match accl rows exactly
    float* og = out + ((size_t)(b * 1024 + i0 + w * 16)) * 1024 + t;
    #pragma unroll
    for (int reg = 0; reg < 4; ++reg) {
        const int   r    = q * 4 + reg;
        const float linv = 1.0f / accl[reg];
        #pragma unroll
        for (int nt = 0; nt < 8; ++nt) {
            float v = acc[nt][reg] * linv;
            v = v > 0.f ? v : __expf(v) - 1.f;
            og[(size_t)r * 1024 + (nt * 16 + m) * 8] = v;
        }
    }
}

// ---------------------------------------------------------------------------
extern "C" void kernel_launch(void* const* d_in, const int* in_sizes, int n_in,
                              void* d_out, int out_size, void* d_ws, size_t ws_size,
                              hipStream_t stream) {
    const float* x   = (const float*)d_in[0];   // (8,1024,64,8)
    const float* adj = (const float*)d_in[1];   // (1024,1024)
    const float* W   = (const float*)d_in[2];   // (64,128)
    const float* a   = (const float*)d_in[3];   // (256,1)
    float* out = (float*)d_out;                 // (8,1024,128,8)

    uint4*         Whf  = (uint4*)d_ws;                        // 1048576 uint4 = 16 MB
    float*         Wh1  = (float*)(Whf + 1048576);             // 65536 f
    float*         Wh2  = Wh1 + 65536;                         // 65536 f
    unsigned char* adjb = (unsigned char*)(Wh2 + 65536);       // 131072 B

    k_wh  <<<512, 512, 0, stream>>>(x, W, a, Whf, Wh1, Wh2);
    k_adjb<<<512, 256, 0, stream>>>(adj, adjb);
    k_agg <<<512, 512, 0, stream>>>(Whf, Wh1, Wh2, adjb, out);
}

// Round 6
// 152.212 us; speedup vs baseline: 1.0501x; 1.0501x over previous
//
#include <hip/hip_runtime.h>
#include <math.h>
#include <stdint.h>

#define ALPHA 0.2f

typedef __attribute__((ext_vector_type(8))) short bf16x8;
typedef __attribute__((ext_vector_type(4))) float f32x4;

__device__ __forceinline__ uint32_t pack_bf16(float a, float b) {
    return ((__float_as_uint(a) + 0x8000u) >> 16) |
           ((__float_as_uint(b) + 0x8000u) & 0xFFFF0000u);
}

// ---------------------------------------------------------------------------
// Kernel 1: k_wh — Wh = (x^T)W fused transpose-GEMM, emitting Wh directly in
// MFMA B-fragment layout (bf16), plus fp32 Wh1/Wh2 score vectors.
// Same structure as round 5 EXCEPT: no min-waves launch bound (round 5's
// (512,4) capped VGPR at 128 and likely spilled to scratch).
// ---------------------------------------------------------------------------
__global__ __launch_bounds__(512) void k_wh(const float* __restrict__ x,
                                            const float* __restrict__ W,
                                            const float* __restrict__ a,
                                            uint4* __restrict__ Whf,
                                            float* __restrict__ Wh1,
                                            float* __restrict__ Wh2) {
    __shared__ float xs[16 * 512];        // 32 KB
    __shared__ float Wv[128 * 68];        // 34.8 KB

    const int tid = threadIdx.x;
    const int b   = blockIdx.x & 7;
    const int jt  = blockIdx.x >> 3;      // 0..63 (16-row tiles)

    // stage x: 16 rows x 512 floats = 2048 float4
    const float4* xg4 = (const float4*)(x + (size_t)(b * 1024 + jt * 16) * 512);
    #pragma unroll
    for (int i = 0; i < 4; ++i) {
        int    idx = tid + i * 512;       // 0..2047
        float4 v   = xg4[idx];
        int jl  = idx >> 7;               // 0..15
        int rem = idx & 127;
        int f   = rem >> 1;               // 0..63
        int tq  = rem & 1;                // t = tq*4 + c
        int kk  = f ^ ((jl >> 2) << 2);   // swizzle by consumer k-quad
        float* dst = &xs[jl * 512 + (tq * 4) * 64 + kk];
        dst[0]   = v.x;
        dst[64]  = v.y;
        dst[128] = v.z;
        dst[192] = v.w;
    }
    // stage Wv[o][k] = W[k][o], k-group swizzled by (o>>3)&7 (2-way staging)
    const float4* Wg4 = (const float4*)W;
    #pragma unroll
    for (int i = 0; i < 4; ++i) {
        int    idx = tid + i * 512;       // 0..2047
        float4 v   = Wg4[idx];
        int k  = idx >> 5;                // 0..63
        int o0 = (idx & 31) * 4;
        #pragma unroll
        for (int c = 0; c < 4; ++c) {
            int o   = o0 + c;
            int adr = o * 68 + ((((k >> 2) ^ ((o >> 3) & 7)) << 2) | (k & 3));
            Wv[adr] = (&v.x)[c];
        }
    }
    __syncthreads();

    const int w  = tid >> 6;              // wave = t (0..7)
    const int l  = tid & 63;
    const int q  = l >> 4;
    const int om = l & 15;
    const int t  = w;

    float acc[4][8];                      // [jj][nt]
    #pragma unroll
    for (int jj = 0; jj < 4; ++jj)
        #pragma unroll
        for (int nt = 0; nt < 8; ++nt) acc[jj][nt] = 0.f;

    for (int kc = 0; kc < 64; kc += 4) {
        float4 xv[4], wv[8];
        const int kx = kc ^ (q << 2);
        #pragma unroll
        for (int jj = 0; jj < 4; ++jj)
            xv[jj] = *(const float4*)&xs[(q * 4 + jj) * 512 + t * 64 + kx];
        #pragma unroll
        for (int nt = 0; nt < 8; ++nt) {
            int og  = nt * 16 + om;
            int grp = (kc >> 2) ^ ((nt * 2 + (om >> 3)) & 7);
            wv[nt]  = *(const float4*)&Wv[og * 68 + grp * 4];
        }
        #pragma unroll
        for (int jj = 0; jj < 4; ++jj) {
            #pragma unroll
            for (int nt = 0; nt < 8; ++nt) {
                float s = acc[jj][nt];
                s = fmaf(xv[jj].x, wv[nt].x, s);
                s = fmaf(xv[jj].y, wv[nt].y, s);
                s = fmaf(xv[jj].z, wv[nt].z, s);
                s = fmaf(xv[jj].w, wv[nt].w, s);
                acc[jj][nt] = s;
            }
        }
    }

    const int bt = b * 8 + t;

    // Wh1/Wh2: dot with a1/a2 over o, reduce across the 16 om-lanes
    float a1v[8], a2v[8];
    #pragma unroll
    for (int nt = 0; nt < 8; ++nt) {
        a1v[nt] = a[nt * 16 + om];
        a2v[nt] = a[128 + nt * 16 + om];
    }
    #pragma unroll
    for (int jj = 0; jj < 4; ++jj) {
        float s1 = 0.f, s2 = 0.f;
        #pragma unroll
        for (int nt = 0; nt < 8; ++nt) {
            s1 = fmaf(acc[jj][nt], a1v[nt], s1);
            s2 = fmaf(acc[jj][nt], a2v[nt], s2);
        }
        #pragma unroll
        for (int off = 1; off < 16; off <<= 1) {
            s1 += __shfl_xor(s1, off);
            s2 += __shfl_xor(s2, off);
        }
        if (om == 0) {
            int j = jt * 16 + q * 4 + jj;
            Wh1[bt * 1024 + j] = s1;
            Wh2[bt * 1024 + j] = s2;
        }
    }

    // frag half-store: uint2 per nt (regs 2(q&1), 2(q&1)+1 of frag-lane q8,om)
    const int    q8l   = ((jt & 1) << 1) | (q >> 1);
    const int    l8    = (q8l << 4) | om;
    const size_t fbase = (size_t)(bt * 32 + (jt >> 1)) * 8;
    #pragma unroll
    for (int nt = 0; nt < 8; ++nt) {
        uint2 st;
        st.x = pack_bf16(acc[0][nt], acc[1][nt]);
        st.y = pack_bf16(acc[2][nt], acc[3][nt]);
        char* p = (char*)(Whf + (fbase + nt) * 64 + l8) + ((q & 1) << 3);
        *(uint2*)p = st;
    }
}

// ---------------------------------------------------------------------------
// Kernel 2: adj -> byte bitmask adjb[i][j/8] (128 KB)
// ---------------------------------------------------------------------------
__global__ __launch_bounds__(256) void k_adjb(const float* __restrict__ adj,
                                              unsigned char* __restrict__ adjb) {
    int idx = blockIdx.x * 256 + threadIdx.x;       // 0..131071
    const float4* a4 = (const float4*)adj + idx * 2;
    float4 v0 = a4[0], v1 = a4[1];
    unsigned int by = 0;
    by |= (v0.x > 0.f) ? 1u : 0u;
    by |= (v0.y > 0.f) ? 2u : 0u;
    by |= (v0.z > 0.f) ? 4u : 0u;
    by |= (v0.w > 0.f) ? 8u : 0u;
    by |= (v1.x > 0.f) ? 16u : 0u;
    by |= (v1.y > 0.f) ? 32u : 0u;
    by |= (v1.z > 0.f) ? 64u : 0u;
    by |= (v1.w > 0.f) ? 128u : 0u;
    adjb[idx] = (unsigned char)by;
}

// ---------------------------------------------------------------------------
// Kernel 3: k_agg — dense flash aggregation, factored scores + MFMA PV.
// ROUND-6 RESTRUCTURE: the per-s 8 KB B-frag tile is staged into LDS ONCE
// per block (register-prefetch double buffer, overlapped with compute) and
// shared by all 4 waves via ds_read_b128 — removes the per-wave serialized
// L2 gather stream that bounded round 5 (1 GB of duplicated dwordx4 loads).
// Each wave now owns 32 rows (2 A-frags) so per-plane wave count halves.
//
// Grid 512: blockIdx = ((itile*8 + t)*8 + b) -> XCD = b (Whf plane pinned).
// Block 256 = 4 waves x 32 rows = 128 rows. 2 blocks/CU (~42 KB LDS).
// ---------------------------------------------------------------------------
__global__ __launch_bounds__(256, 2) void k_agg(const uint4* __restrict__ Whf,
                                                const float* __restrict__ Wh1,
                                                const float* __restrict__ Wh2,
                                                const unsigned char* __restrict__ adjb,
                                                float* __restrict__ out) {
    __shared__ __attribute__((aligned(16))) uint4  bstage[2][512];   // 16 KB
    __shared__ __attribute__((aligned(16))) float2 efs[1024];        // 8 KB [E,F]
    __shared__ unsigned int adjs_u[128 * 33];                        // 16.5 KB
    __shared__ float wh1s[128];
    __shared__ float m2s[4];

    const int tid   = threadIdx.x;
    const int b     = blockIdx.x & 7;
    const int t     = (blockIdx.x >> 3) & 7;
    const int itile = blockIdx.x >> 6;            // 0..7
    const int bt    = b * 8 + t;
    const int i0    = itile * 128;

    const int w = tid >> 6;                       // wave 0..3
    const int l = tid & 63;
    const int q = l >> 4;                         // k-quad
    const int m = l & 15;

    const uint4* plane = Whf + (size_t)bt * 16384;   // 32 s-tiles x 512 uint4

    // prefetch s=0 B-tile + stage E/F (+max), Wh1 slice, adj bits
    uint4 pf0 = plane[tid];
    uint4 pf1 = plane[256 + tid];

    const float* wh2g = Wh2 + bt * 1024;
    float mx = -1e30f;
    for (int j = tid; j < 1024; j += 256) {
        float h2 = wh2g[j];
        float2 ef;
        ef.x = __expf(h2);
        ef.y = __expf(ALPHA * h2);
        efs[j] = ef;
        mx = fmaxf(mx, h2);
    }
    #pragma unroll
    for (int off = 1; off < 64; off <<= 1) mx = fmaxf(mx, __shfl_xor(mx, off));
    if (l == 0) m2s[w] = mx;
    if (tid < 128) wh1s[tid] = Wh1[bt * 1024 + i0 + tid];
    const unsigned int* adjg = (const unsigned int*)(adjb + i0 * 128);
    for (int idx = tid; idx < 4096; idx += 256)
        adjs_u[(idx >> 5) * 33 + (idx & 31)] = adjg[idx];

    bstage[0][tid]       = pf0;
    bstage[0][tid + 256] = pf1;
    __syncthreads();

    float M2 = fmaxf(fmaxf(m2s[0], m2s[1]), fmaxf(m2s[2], m2s[3]));

    // per-ms (2 x 16-row A-tiles) scalars
    float h1v[2], Af[2], Bf[2], G[2];
    int   arow[2];
    #pragma unroll
    for (int ms = 0; ms < 2; ++ms) {
        int   row = w * 32 + ms * 16 + m;
        float h1  = wh1s[row];
        float e0  = h1 + M2;
        float mp  = fmaxf(e0, ALPHA * e0);        // p <= 1 for all (i,j)
        h1v[ms]  = h1;
        Af[ms]   = __expf(h1 - mp);
        Bf[ms]   = __expf(ALPHA * h1 - mp);
        G[ms]    = __expf(-h1);
        arow[ms] = row * 33;
    }

    f32x4 acc[2][8];
    #pragma unroll
    for (int ms = 0; ms < 2; ++ms)
        #pragma unroll
        for (int nt = 0; nt < 8; ++nt) acc[ms][nt] = (f32x4){0.f, 0.f, 0.f, 0.f};
    f32x4 accl[2] = {(f32x4){0.f, 0.f, 0.f, 0.f}, (f32x4){0.f, 0.f, 0.f, 0.f}};

    bf16x8 ones;
    #pragma unroll
    for (int i = 0; i < 8; ++i) ones[i] = (short)0x3F80;

    for (int s = 0; s < 32; ++s) {
        // prefetch next s-tile (consumed after compute; overlaps with it)
        if (s + 1 < 32) {
            pf0 = plane[(s + 1) * 512 + tid];
            pf1 = plane[(s + 1) * 512 + 256 + tid];
        }

        // E/F for j = s*32 + q*8 + jj (16-lane broadcast groups, 2-way banks)
        const float* eb = (const float*)&efs[s * 32 + q * 8];
        float4 ef01 = *(const float4*)(eb + 0);
        float4 ef23 = *(const float4*)(eb + 4);
        float4 ef45 = *(const float4*)(eb + 8);
        float4 ef67 = *(const float4*)(eb + 12);
        float E[8], F[8];
        E[0] = ef01.x; F[0] = ef01.y; E[1] = ef01.z; F[1] = ef01.w;
        E[2] = ef23.x; F[2] = ef23.y; E[3] = ef23.z; F[3] = ef23.w;
        E[4] = ef45.x; F[4] = ef45.y; E[5] = ef45.z; F[5] = ef45.w;
        E[6] = ef67.x; F[6] = ef67.y; E[7] = ef67.z; F[7] = ef67.w;

        bf16x8 afr[2];
        #pragma unroll
        for (int ms = 0; ms < 2; ++ms) {
            const unsigned int dw = adjs_u[arow[ms] + s];
            float p[8];
            #pragma unroll
            for (int jj = 0; jj < 8; ++jj) {
                bool  cond = E[jj] > G[ms];                    // h1+h2 > 0
                float pr   = (cond ? Af[ms] : Bf[ms]) * (cond ? E[jj] : F[jj]);
                p[jj] = ((dw >> (q * 8 + jj)) & 1u) ? pr : 0.0f;
            }
            union { uint32_t u[4]; bf16x8 v; } pk;
            #pragma unroll
            for (int pr2 = 0; pr2 < 4; ++pr2)
                pk.u[pr2] = pack_bf16(p[2 * pr2], p[2 * pr2 + 1]);
            afr[ms] = pk.v;
        }

        // B-frags from LDS (ds_read_b128, conflict-free), shared by all waves
        const uint4* bp = &bstage[s & 1][l];
        #pragma unroll
        for (int nt = 0; nt < 8; ++nt) {
            union { uint4 u; bf16x8 v; } br;
            br.u = bp[nt * 64];
            acc[0][nt] = __builtin_amdgcn_mfma_f32_16x16x32_bf16(afr[0], br.v, acc[0][nt], 0, 0, 0);
            acc[1][nt] = __builtin_amdgcn_mfma_f32_16x16x32_bf16(afr[1], br.v, acc[1][nt], 0, 0, 0);
        }
        accl[0] = __builtin_amdgcn_mfma_f32_16x16x32_bf16(afr[0], ones, accl[0], 0, 0, 0);
        accl[1] = __builtin_amdgcn_mfma_f32_16x16x32_bf16(afr[1], ones, accl[1], 0, 0, 0);

        if (s + 1 < 32) {
            bstage[(s + 1) & 1][tid]       = pf0;
            bstage[(s + 1) & 1][tid + 256] = pf1;
        }
        __syncthreads();
    }

    // epilogue: D-layout rows r = q*4+reg; accl rows match exactly
    #pragma unroll
    for (int ms = 0; ms < 2; ++ms) {
        float* og = out + ((size_t)(b * 1024 + i0 + w * 32 + ms * 16)) * 1024 + t;
        #pragma unroll
        for (int reg = 0; reg < 4; ++reg) {
            const int   r    = q * 4 + reg;
            const float linv = 1.0f / accl[ms][reg];
            #pragma unroll
            for (int nt = 0; nt < 8; ++nt) {
                float v = acc[ms][nt][reg] * linv;
                v = v > 0.f ? v : __expf(v) - 1.f;
                og[(size_t)r * 1024 + (nt * 16 + m) * 8] = v;
            }
        }
    }
}

// ---------------------------------------------------------------------------
extern "C" void kernel_launch(void* const* d_in, const int* in_sizes, int n_in,
                              void* d_out, int out_size, void* d_ws, size_t ws_size,
                              hipStream_t stream) {
    const float* x   = (const float*)d_in[0];   // (8,1024,64,8)
    const float* adj = (const float*)d_in[1];   // (1024,1024)
    const float* W   = (const float*)d_in[2];   // (64,128)
    const float* a   = (const float*)d_in[3];   // (256,1)
    float* out = (float*)d_out;                 // (8,1024,128,8)

    uint4*         Whf  = (uint4*)d_ws;                        // 1048576 uint4 = 16 MB
    float*         Wh1  = (float*)(Whf + 1048576);             // 65536 f
    float*         Wh2  = Wh1 + 65536;                         // 65536 f
    unsigned char* adjb = (unsigned char*)(Wh2 + 65536);       // 131072 B

    k_wh  <<<512, 512, 0, stream>>>(x, W, a, Whf, Wh1, Wh2);
    k_adjb<<<512, 256, 0, stream>>>(adj, adjb);
    k_agg <<<512, 256, 0, stream>>>(Whf, Wh1, Wh2, adjb, out);
}

// Round 7
// 147.258 us; speedup vs baseline: 1.0854x; 1.0336x over previous
//
#include <hip/hip_runtime.h>
#include <math.h>
#include <stdint.h>

#define ALPHA 0.2f

typedef __attribute__((ext_vector_type(8))) short bf16x8;
typedef __attribute__((ext_vector_type(4))) float f32x4;

__device__ __forceinline__ uint32_t pack_bf16(float a, float b) {
    return ((__float_as_uint(a) + 0x8000u) >> 16) |
           ((__float_as_uint(b) + 0x8000u) & 0xFFFF0000u);
}

// ---------------------------------------------------------------------------
// Kernel 1: k_wh — Wh = (x^T)W fused transpose-GEMM, emitting Wh directly in
// MFMA B-fragment layout (bf16), plus fp32 Wh1/Wh2 score vectors.
// (unchanged from round 6 — isolating the k_agg experiment)
// ---------------------------------------------------------------------------
__global__ __launch_bounds__(512) void k_wh(const float* __restrict__ x,
                                            const float* __restrict__ W,
                                            const float* __restrict__ a,
                                            uint4* __restrict__ Whf,
                                            float* __restrict__ Wh1,
                                            float* __restrict__ Wh2) {
    __shared__ float xs[16 * 512];        // 32 KB
    __shared__ float Wv[128 * 68];        // 34.8 KB

    const int tid = threadIdx.x;
    const int b   = blockIdx.x & 7;
    const int jt  = blockIdx.x >> 3;      // 0..63 (16-row tiles)

    const float4* xg4 = (const float4*)(x + (size_t)(b * 1024 + jt * 16) * 512);
    #pragma unroll
    for (int i = 0; i < 4; ++i) {
        int    idx = tid + i * 512;       // 0..2047
        float4 v   = xg4[idx];
        int jl  = idx >> 7;
        int rem = idx & 127;
        int f   = rem >> 1;
        int tq  = rem & 1;
        int kk  = f ^ ((jl >> 2) << 2);
        float* dst = &xs[jl * 512 + (tq * 4) * 64 + kk];
        dst[0]   = v.x;
        dst[64]  = v.y;
        dst[128] = v.z;
        dst[192] = v.w;
    }
    const float4* Wg4 = (const float4*)W;
    #pragma unroll
    for (int i = 0; i < 4; ++i) {
        int    idx = tid + i * 512;       // 0..2047
        float4 v   = Wg4[idx];
        int k  = idx >> 5;
        int o0 = (idx & 31) * 4;
        #pragma unroll
        for (int c = 0; c < 4; ++c) {
            int o   = o0 + c;
            int adr = o * 68 + ((((k >> 2) ^ ((o >> 3) & 7)) << 2) | (k & 3));
            Wv[adr] = (&v.x)[c];
        }
    }
    __syncthreads();

    const int w  = tid >> 6;              // wave = t (0..7)
    const int l  = tid & 63;
    const int q  = l >> 4;
    const int om = l & 15;
    const int t  = w;

    float acc[4][8];
    #pragma unroll
    for (int jj = 0; jj < 4; ++jj)
        #pragma unroll
        for (int nt = 0; nt < 8; ++nt) acc[jj][nt] = 0.f;

    for (int kc = 0; kc < 64; kc += 4) {
        float4 xv[4], wv[8];
        const int kx = kc ^ (q << 2);
        #pragma unroll
        for (int jj = 0; jj < 4; ++jj)
            xv[jj] = *(const float4*)&xs[(q * 4 + jj) * 512 + t * 64 + kx];
        #pragma unroll
        for (int nt = 0; nt < 8; ++nt) {
            int og  = nt * 16 + om;
            int grp = (kc >> 2) ^ ((nt * 2 + (om >> 3)) & 7);
            wv[nt]  = *(const float4*)&Wv[og * 68 + grp * 4];
        }
        #pragma unroll
        for (int jj = 0; jj < 4; ++jj) {
            #pragma unroll
            for (int nt = 0; nt < 8; ++nt) {
                float s = acc[jj][nt];
                s = fmaf(xv[jj].x, wv[nt].x, s);
                s = fmaf(xv[jj].y, wv[nt].y, s);
                s = fmaf(xv[jj].z, wv[nt].z, s);
                s = fmaf(xv[jj].w, wv[nt].w, s);
                acc[jj][nt] = s;
            }
        }
    }

    const int bt = b * 8 + t;

    float a1v[8], a2v[8];
    #pragma unroll
    for (int nt = 0; nt < 8; ++nt) {
        a1v[nt] = a[nt * 16 + om];
        a2v[nt] = a[128 + nt * 16 + om];
    }
    #pragma unroll
    for (int jj = 0; jj < 4; ++jj) {
        float s1 = 0.f, s2 = 0.f;
        #pragma unroll
        for (int nt = 0; nt < 8; ++nt) {
            s1 = fmaf(acc[jj][nt], a1v[nt], s1);
            s2 = fmaf(acc[jj][nt], a2v[nt], s2);
        }
        #pragma unroll
        for (int off = 1; off < 16; off <<= 1) {
            s1 += __shfl_xor(s1, off);
            s2 += __shfl_xor(s2, off);
        }
        if (om == 0) {
            int j = jt * 16 + q * 4 + jj;
            Wh1[bt * 1024 + j] = s1;
            Wh2[bt * 1024 + j] = s2;
        }
    }

    const int    q8l   = ((jt & 1) << 1) | (q >> 1);
    const int    l8    = (q8l << 4) | om;
    const size_t fbase = (size_t)(bt * 32 + (jt >> 1)) * 8;
    #pragma unroll
    for (int nt = 0; nt < 8; ++nt) {
        uint2 st;
        st.x = pack_bf16(acc[0][nt], acc[1][nt]);
        st.y = pack_bf16(acc[2][nt], acc[3][nt]);
        char* p = (char*)(Whf + (fbase + nt) * 64 + l8) + ((q & 1) << 3);
        *(uint2*)p = st;
    }
}

// ---------------------------------------------------------------------------
// Kernel 2: adj -> TRANSPOSED byte bitmask adjq[i][q][s] (128 KB):
//   adjq[i*128 + q*32 + s] holds bits jj for j = s*32 + q*8 + jj.
// k_agg lane (row, q) then reads its whole 32-step mask as TWO uint4s.
// ---------------------------------------------------------------------------
__global__ __launch_bounds__(256) void k_adjb(const float* __restrict__ adj,
                                              unsigned char* __restrict__ adjq) {
    int idx = blockIdx.x * 256 + threadIdx.x;       // 0..131071
    int i   = idx >> 7;
    int pos = idx & 127;                            // old byte pos = s*4+q
    const float4* a4 = (const float4*)adj + idx * 2;
    float4 v0 = a4[0], v1 = a4[1];
    unsigned int by = 0;
    by |= (v0.x > 0.f) ? 1u : 0u;
    by |= (v0.y > 0.f) ? 2u : 0u;
    by |= (v0.z > 0.f) ? 4u : 0u;
    by |= (v0.w > 0.f) ? 8u : 0u;
    by |= (v1.x > 0.f) ? 16u : 0u;
    by |= (v1.y > 0.f) ? 32u : 0u;
    by |= (v1.z > 0.f) ? 64u : 0u;
    by |= (v1.w > 0.f) ? 128u : 0u;
    adjq[i * 128 + (pos & 3) * 32 + (pos >> 2)] = (unsigned char)by;
}

// ---------------------------------------------------------------------------
// Kernel 3: k_agg — dense flash aggregation, factored scores + MFMA PV.
// ROUND-7: occupancy attack. Block 512 = 8 waves x 16 rows; LDS trimmed to
// ~24.6 KB (adj mask moved to 2 VGPR uint4s via the adjq layout; s-loop
// fully unrolled so byte extraction is static) -> 2 blocks/CU = 16 waves/CU
// (was 8). B-tile still staged once per block and shared via ds_read_b128;
// per-CU LDS traffic unchanged, latency hiding doubled.
//
// Grid 512: blockIdx = ((itile*8 + t)*8 + b) -> XCD = b (Whf plane pinned).
// ---------------------------------------------------------------------------
__global__ __launch_bounds__(512, 4) void k_agg(const uint4* __restrict__ Whf,
                                                const float* __restrict__ Wh1,
                                                const float* __restrict__ Wh2,
                                                const unsigned char* __restrict__ adjq,
                                                float* __restrict__ out) {
    __shared__ __attribute__((aligned(16))) uint4  bstage[2][512];   // 16 KB
    __shared__ __attribute__((aligned(16))) float2 efs[1024];        // 8 KB [E,F]
    __shared__ float wh1s[128];
    __shared__ float m2s[8];

    const int tid   = threadIdx.x;
    const int b     = blockIdx.x & 7;
    const int t     = (blockIdx.x >> 3) & 7;
    const int itile = blockIdx.x >> 6;            // 0..7
    const int bt    = b * 8 + t;
    const int i0    = itile * 128;

    const int w = tid >> 6;                       // wave 0..7
    const int l = tid & 63;
    const int q = l >> 4;                         // k-quad
    const int m = l & 15;
    const int row = w * 16 + m;                   // 0..127

    const uint4* plane = Whf + (size_t)bt * 16384;   // 32 s-tiles x 512 uint4

    // prefetch s=0 B-tile (1 uint4/thread) + adj mask regs + stage E/F, Wh1
    uint4 pf = plane[tid];
    const uint4* amask = (const uint4*)(adjq + (i0 + row) * 128 + q * 32);
    uint4 adj0 = amask[0];
    uint4 adj1 = amask[1];

    const float* wh2g = Wh2 + bt * 1024;
    float mx = -1e30f;
    #pragma unroll
    for (int rep = 0; rep < 2; ++rep) {
        int   j  = tid + rep * 512;
        float h2 = wh2g[j];
        float2 ef;
        ef.x = __expf(h2);
        ef.y = __expf(ALPHA * h2);
        efs[j] = ef;
        mx = fmaxf(mx, h2);
    }
    #pragma unroll
    for (int off = 1; off < 64; off <<= 1) mx = fmaxf(mx, __shfl_xor(mx, off));
    if (l == 0) m2s[w] = mx;
    if (tid < 128) wh1s[tid] = Wh1[bt * 1024 + i0 + tid];

    bstage[0][tid] = pf;
    __syncthreads();

    float M2 = m2s[0];
    #pragma unroll
    for (int i = 1; i < 8; ++i) M2 = fmaxf(M2, m2s[i]);

    const float h1 = wh1s[row];
    const float e0 = h1 + M2;
    const float mp = fmaxf(e0, ALPHA * e0);       // p <= 1 for all (i,j)
    const float Af = __expf(h1 - mp);
    const float Bf = __expf(ALPHA * h1 - mp);
    const float G  = __expf(-h1);

    f32x4 acc[8];
    #pragma unroll
    for (int nt = 0; nt < 8; ++nt) acc[nt] = (f32x4){0.f, 0.f, 0.f, 0.f};
    f32x4 accl = (f32x4){0.f, 0.f, 0.f, 0.f};

    bf16x8 ones;
    #pragma unroll
    for (int i = 0; i < 8; ++i) ones[i] = (short)0x3F80;

    #pragma unroll
    for (int s = 0; s < 32; ++s) {
        if (s + 1 < 32) pf = plane[(s + 1) * 512 + tid];

        // E/F for j = s*32 + q*8 + jj (4 distinct addrs/wave — broadcast)
        const float* eb = (const float*)&efs[s * 32 + q * 8];
        float4 ef01 = *(const float4*)(eb + 0);
        float4 ef23 = *(const float4*)(eb + 4);
        float4 ef45 = *(const float4*)(eb + 8);
        float4 ef67 = *(const float4*)(eb + 12);
        float E[8], F[8];
        E[0] = ef01.x; F[0] = ef01.y; E[1] = ef01.z; F[1] = ef01.w;
        E[2] = ef23.x; F[2] = ef23.y; E[3] = ef23.z; F[3] = ef23.w;
        E[4] = ef45.x; F[4] = ef45.y; E[5] = ef45.z; F[5] = ef45.w;
        E[6] = ef67.x; F[6] = ef67.y; E[7] = ef67.z; F[7] = ef67.w;

        // adj byte for this (row, q, s) — static select after full unroll
        const uint4   av = (s < 16) ? adj0 : adj1;
        const int     c  = (s >> 2) & 3;
        const uint32_t cw = (c == 0) ? av.x : (c == 1) ? av.y : (c == 2) ? av.z : av.w;
        const uint32_t by = (cw >> ((s & 3) * 8)) & 0xFFu;

        float p[8];
        #pragma unroll
        for (int jj = 0; jj < 8; ++jj) {
            bool  cond = E[jj] > G;                       // h1+h2 > 0
            float pr   = (cond ? Af : Bf) * (cond ? E[jj] : F[jj]);
            p[jj] = ((by >> jj) & 1u) ? pr : 0.0f;
        }
        union { uint32_t u[4]; bf16x8 v; } pk;
        #pragma unroll
        for (int pr2 = 0; pr2 < 4; ++pr2)
            pk.u[pr2] = pack_bf16(p[2 * pr2], p[2 * pr2 + 1]);

        // B-frags from LDS (shared by all 8 waves)
        const uint4* bp = &bstage[s & 1][l];
        #pragma unroll
        for (int nt = 0; nt < 8; ++nt) {
            union { uint4 u; bf16x8 v; } br;
            br.u = bp[nt * 64];
            acc[nt] = __builtin_amdgcn_mfma_f32_16x16x32_bf16(pk.v, br.v, acc[nt], 0, 0, 0);
        }
        accl = __builtin_amdgcn_mfma_f32_16x16x32_bf16(pk.v, ones, accl, 0, 0, 0);

        if (s + 1 < 32) bstage[(s + 1) & 1][tid] = pf;
        __syncthreads();
    }

    // epilogue: D-layout rows r = q*4+reg; accl rows match exactly
    float* og = out + ((size_t)(b * 1024 + i0 + w * 16)) * 1024 + t;
    #pragma unroll
    for (int reg = 0; reg < 4; ++reg) {
        const int   r    = q * 4 + reg;
        const float linv = 1.0f / accl[reg];
        #pragma unroll
        for (int nt = 0; nt < 8; ++nt) {
            float v = acc[nt][reg] * linv;
            v = v > 0.f ? v : __expf(v) - 1.f;
            og[(size_t)r * 1024 + (nt * 16 + m) * 8] = v;
        }
    }
}

// ---------------------------------------------------------------------------
extern "C" void kernel_launch(void* const* d_in, const int* in_sizes, int n_in,
                              void* d_out, int out_size, void* d_ws, size_t ws_size,
                              hipStream_t stream) {
    const float* x   = (const float*)d_in[0];   // (8,1024,64,8)
    const float* adj = (const float*)d_in[1];   // (1024,1024)
    const float* W   = (const float*)d_in[2];   // (64,128)
    const float* a   = (const float*)d_in[3];   // (256,1)
    float* out = (float*)d_out;                 // (8,1024,128,8)

    uint4*         Whf  = (uint4*)d_ws;                        // 1048576 uint4 = 16 MB
    float*         Wh1  = (float*)(Whf + 1048576);             // 65536 f
    float*         Wh2  = Wh1 + 65536;                         // 65536 f
    unsigned char* adjq = (unsigned char*)(Wh2 + 65536);       // 131072 B

    k_wh  <<<512, 512, 0, stream>>>(x, W, a, Whf, Wh1, Wh2);
    k_adjb<<<512, 256, 0, stream>>>(adj, adjq);
    k_agg <<<512, 512, 0, stream>>>(Whf, Wh1, Wh2, adjq, out);
}